// Round 14
// baseline (320.135 us; speedup 1.0000x reference)
//
#include <hip/hip_runtime.h>

#define B_  8
#define S_  4096
#define D_  768
#define H_  12
#define M_  (B_ * S_)      // 32768
#define NQKV_ 2304         // 3*D
#define NTILES 12          // 768 / 64

typedef unsigned short u16;
typedef __attribute__((ext_vector_type(4))) float  f32x4;
typedef __attribute__((ext_vector_type(8))) __bf16 bf16x8;
typedef __attribute__((ext_vector_type(4))) u16    u16x4;

#define GAS __attribute__((address_space(1)))
#define LAS __attribute__((address_space(3)))

__device__ __forceinline__ u16 f2bf(float f) {
    unsigned u = __float_as_uint(f);
    u += 0x7FFF + ((u >> 16) & 1);          // round-to-nearest-even
    return (u16)(u >> 16);
}
__device__ __forceinline__ float bf2f(u16 h) {
    return __uint_as_float(((unsigned)h) << 16);
}

__device__ __forceinline__ void gload_lds16(const void* g, void* l) {
    __builtin_amdgcn_global_load_lds((const GAS void*)g, (LAS void*)l, 16, 0, 0);
}

// bijective XCD swizzle (nwg % 8 == 0): each XCD gets a contiguous work chunk
__device__ __forceinline__ int xcd_swz(int bid, int nwg) {
    return (bid & 7) * (nwg >> 3) + (bid >> 3);
}

// ---------------- cast x (f32 -> bf16) ----------------
__global__ __launch_bounds__(256) void castx_kernel(const float* __restrict__ x,
                                                    u16* __restrict__ xb) {
    const int i = blockIdx.x * 256 + threadIdx.x;
    const float4 v = ((const float4*)x)[i];
    u16x4 o;
    o.x = f2bf(v.x); o.y = f2bf(v.y); o.z = f2bf(v.z); o.w = f2bf(v.w);
    ((u16x4*)xb)[i] = o;
}

// ---------------- weight transpose+cast: W[k][n] f32 -> Wb[n][k] bf16 ----------------
__global__ __launch_bounds__(256) void wtrans_kernel(const float* __restrict__ Wq,
                                                     const float* __restrict__ Wk,
                                                     const float* __restrict__ Wv,
                                                     const float* __restrict__ Wo,
                                                     u16* __restrict__ Wb) {
    const float* W = (blockIdx.z == 0) ? Wq : (blockIdx.z == 1) ? Wk
                   : (blockIdx.z == 2) ? Wv : Wo;
    u16* O = Wb + (size_t)blockIdx.z * D_ * D_;
    __shared__ float tile[32][33];
    const int tx = threadIdx.x & 31, ty = threadIdx.x >> 5;  // 32x8
    const int k0 = blockIdx.y * 32, n0 = blockIdx.x * 32;
#pragma unroll
    for (int j = 0; j < 4; j++)
        tile[ty + j * 8][tx] = W[(size_t)(k0 + ty + j * 8) * D_ + n0 + tx];
    __syncthreads();
#pragma unroll
    for (int j = 0; j < 4; j++)
        O[(size_t)(n0 + ty + j * 8) * D_ + k0 + tx] = f2bf(tile[tx][ty + j * 8]);
}

// ========= PERSISTENT 128x128 double-buffered bf16 MFMA GEMM (2 blk/CU) =========
// Grid = 512 blocks exactly (2/CU).  Each block processes NW consecutive work
// items (nt-fastest -> A-panel L2 reuse) with ONE continuous double-buffer
// pipeline: at kt==11 it stages the NEXT ITEM's kt0 instead of draining.
// Base schedule = R11 (fastest measured; race-free by full __syncthreads per
// K-tile): 512 thr = 8 waves (2M x 4N), per-wave C = 64x32 (acc 32 regs).
// LDS 64 KiB = 2 x (A 128rows x 128B + B 128rows x 128B).
// Swizzle (VERIFIED 0-conflict, R8/R11/R12): slot s of 128B row R holds
//   global chunk s ^ (R&7); staging pre-swizzles source; reads use
//   slot = chunkgroup ^ (l&7).
// Buffer parity: 12 K-tiles per item (even) -> buf = kt&1 is compile-time and
//   continuous across items.  Epilogue (C-write + acc zero) runs in the kt==11
//   slot, overlapped with the already-issued next-item stage.

#define MFMA8(AF, BF)                                                        \
    __builtin_amdgcn_s_setprio(1);                                           \
    _Pragma("unroll") for (int mi = 0; mi < 4; ++mi)                         \
        _Pragma("unroll") for (int ni = 0; ni < 2; ++ni)                     \
            acc[mi][ni] = __builtin_amdgcn_mfma_f32_16x16x32_bf16(           \
                AF[mi], BF[ni], acc[mi][ni], 0, 0, 0);                       \
    __builtin_amdgcn_s_setprio(0)

#define RD(p, imm) (*(const bf16x8*)((p) + (imm)))

template <int MODE>
__global__ __launch_bounds__(512, 4) void gemmp_kernel(
    const u16* __restrict__ A, const u16* __restrict__ Wb,
    const float* __restrict__ b0, const float* __restrict__ b1,
    const float* __restrict__ b2,
    u16* __restrict__ outb, const u16* __restrict__ xres) {
    extern __shared__ char lds[];    // 65536 B

    const int t = threadIdx.x;
    const int w = t >> 6, l = t & 63;
    const int wm = w >> 2, wn = w & 3;

    const int NTN = (MODE == 0) ? 18 : 6;
    const int NW  = (MODE == 0) ? 9 : 3;
    int work = xcd_swz(blockIdx.x, gridDim.x) * NW;

    // ---- staging lane geometry (pre-swizzled source; 128B rows, 8 slots) ----
    const int lrow = l >> 3;                     // 0..7 within an 8-row gload
    const int schunk = (l & 7) ^ lrow;           // wave rows start at w*16 (≡0 mod 8)

    // ---- ds_read geometry (swizzled slot; verified pattern) ----
    const int ck0 = (((l >> 4) ^ (l & 7)) << 4);         // kh0 slot byte
    const int ck1 = ((((l >> 4) + 4) ^ (l & 7)) << 4);   // kh1 slot byte
    const char* aB = lds + (wm * 64 + (l & 15)) * 128;           // +buf +mi*2048
    const char* bB = lds + 16384 + (wn * 32 + (l & 15)) * 128;   // +buf +ni*2048

    // ---- per-item parameters ----
    int m0, col0, widx;
    const u16 *As, *Bs;
    auto setp = [&](int wk, int& _m0, int& _col0, int& _widx,
                    const u16*& _As, const u16*& _Bs) {
        const int mt = wk / NTN, nt = wk % NTN;
        _m0 = mt * 128;
        _col0 = nt * 128;
        _widx = (MODE == 0) ? (nt / 6) : 3;
        const int n0w = (MODE == 0) ? (nt % 6) * 128 : _col0;
        _As = A + (size_t)(_m0 + w * 16 + lrow) * D_ + schunk * 8;
        _Bs = Wb + (size_t)_widx * (D_ * D_)
                 + (size_t)(n0w + w * 16 + lrow) * D_ + schunk * 8;
    };
    setp(work, m0, col0, widx, As, Bs);

    // stage K-tile kt of item (_A,_B) into buffer at byte-offset bo
    auto STAGE = [&](const u16* _A, const u16* _B, int kt, int bo) {
        const int ko = kt * 64;
        char* da = lds + bo + w * 2048;
        char* db = lds + bo + 16384 + w * 2048;
        gload_lds16(_A + ko, da);
        gload_lds16(_A + ko + 8 * D_, da + 1024);
        gload_lds16(_B + ko, db);
        gload_lds16(_B + ko + 8 * D_, db + 1024);
    };

    f32x4 acc[4][2];
#pragma unroll
    for (int i = 0; i < 4; i++)
#pragma unroll
        for (int j = 0; j < 2; j++) acc[i][j] = (f32x4){0.f, 0.f, 0.f, 0.f};

    // ---- prologue: stage item0 kt0 -> buf0 ----
    STAGE(As, Bs, 0, 0);
    __syncthreads();

    for (int j = 0; j < NW; ++j) {
        // next item's params (used at kt==11)
        int nm0 = m0, ncol0 = col0, nwidx = widx;
        const u16 *nAs = As, *nBs = Bs;
        if (j + 1 < NW) setp(work + 1, nm0, ncol0, nwidx, nAs, nBs);

#pragma unroll
        for (int kt = 0; kt < 12; ++kt) {
            const int cb = (kt & 1) * 32768;
            const int ob = cb ^ 32768;
            if (kt < 11)          STAGE(As, Bs, kt + 1, ob);
            else if (j + 1 < NW)  STAGE(nAs, nBs, 0, ob);

            bf16x8 af[4], bf[2];
            // kh0
#pragma unroll
            for (int mi = 0; mi < 4; ++mi) af[mi] = RD(aB, cb + mi * 2048 + ck0);
#pragma unroll
            for (int ni = 0; ni < 2; ++ni) bf[ni] = RD(bB, cb + ni * 2048 + ck0);
            MFMA8(af, bf);
            // kh1
#pragma unroll
            for (int mi = 0; mi < 4; ++mi) af[mi] = RD(aB, cb + mi * 2048 + ck1);
#pragma unroll
            for (int ni = 0; ni < 2; ++ni) bf[ni] = RD(bB, cb + ni * 2048 + ck1);
            MFMA8(af, bf);

            if (kt == 11) {
                // ---- epilogue for current item (overlaps next-item stage) ----
                const int crow0 = m0 + wm * 64 + ((l >> 4) << 2);
                const int ccol0 = col0 + wn * 32 + (l & 15);
                if (MODE == 0) {
                    const float* bias = (widx == 0) ? b0 : (widx == 1) ? b1 : b2;
                    const int bcol0 = ccol0 - widx * D_;
#pragma unroll
                    for (int mi = 0; mi < 4; ++mi)
#pragma unroll
                        for (int ni = 0; ni < 2; ++ni) {
                            const float bv = bias[bcol0 + ni * 16];
#pragma unroll
                            for (int r = 0; r < 4; ++r)
                                outb[(size_t)(crow0 + mi * 16 + r) * NQKV_
                                     + ccol0 + ni * 16] = f2bf(acc[mi][ni][r] + bv);
                        }
                } else {
#pragma unroll
                    for (int mi = 0; mi < 4; ++mi)
#pragma unroll
                        for (int ni = 0; ni < 2; ++ni) {
                            const int col = ccol0 + ni * 16;
                            const float bv = b0[col];
#pragma unroll
                            for (int r = 0; r < 4; ++r) {
                                const size_t idx =
                                    (size_t)(crow0 + mi * 16 + r) * D_ + col;
                                outb[idx] = f2bf(acc[mi][ni][r] + bv + bf2f(xres[idx]));
                            }
                        }
                }
#pragma unroll
                for (int i = 0; i < 4; i++)
#pragma unroll
                    for (int jj = 0; jj < 2; jj++)
                        acc[i][jj] = (f32x4){0.f, 0.f, 0.f, 0.f};
            }
            __syncthreads();   // full drain: race-free (R11-proven)
        }
        m0 = nm0; col0 = ncol0; widx = nwidx; As = nAs; Bs = nBs; ++work;
    }
}

// ---------------- local attention: one wave per (m, head-quad) ----------------
__global__ __launch_bounds__(256) void attn_kernel(const u16* __restrict__ QKV,
                                                   const float* __restrict__ bk,
                                                   const float* __restrict__ bv,
                                                   u16* __restrict__ att) {
    const int gw = xcd_swz(blockIdx.x, gridDim.x) * 4 + (threadIdx.x >> 6);
    const int l  = threadIdx.x & 63;
    const int hq = gw % 3;             // head-quad index
    const int m  = gw / 3;
    const int s  = m & (S_ - 1);
    const int col = hq * 256 + l * 4;
    const u16* base = QKV + (size_t)m * NQKV_;

    const u16x4 qv = *(const u16x4*)(base + col);
    float qf[4];
#pragma unroll
    for (int j = 0; j < 4; j++) qf[j] = bf2f(qv[j]);

    float sc[5];
#pragma unroll
    for (int i = 0; i < 5; i++) {
        const int sp = s + i - 2;
        float p;
        if (sp >= 0 && sp < S_) {
            const u16x4 kv = *(const u16x4*)(base + (i - 2) * NQKV_ + D_ + col);
            p = qf[0] * bf2f(kv[0]) + qf[1] * bf2f(kv[1])
              + qf[2] * bf2f(kv[2]) + qf[3] * bf2f(kv[3]);
        } else {
            const float4 kb = *(const float4*)(bk + col);
            p = qf[0] * kb.x + qf[1] * kb.y + qf[2] * kb.z + qf[3] * kb.w;
        }
#pragma unroll
        for (int off = 1; off < 16; off <<= 1) p += __shfl_xor(p, off, 64);
        sc[i] = p * 0.125f;
    }
    float mx = sc[0];
#pragma unroll
    for (int i = 1; i < 5; i++) mx = fmaxf(mx, sc[i]);
    float e[5], sum = 0.f;
#pragma unroll
    for (int i = 0; i < 5; i++) { e[i] = __expf(sc[i] - mx); sum += e[i]; }
    const float inv = 1.f / sum;

    float o[4] = {0.f, 0.f, 0.f, 0.f};
#pragma unroll
    for (int i = 0; i < 5; i++) {
        const float wgt = e[i] * inv;
        const int sp = s + i - 2;
        if (sp >= 0 && sp < S_) {
            const u16x4 vv = *(const u16x4*)(base + (i - 2) * NQKV_ + 2 * D_ + col);
#pragma unroll
            for (int j = 0; j < 4; j++) o[j] += wgt * bf2f(vv[j]);
        } else {
            const float4 vb = *(const float4*)(bv + col);
            o[0] += wgt * vb.x; o[1] += wgt * vb.y;
            o[2] += wgt * vb.z; o[3] += wgt * vb.w;
        }
    }
    u16x4 ov;
#pragma unroll
    for (int j = 0; j < 4; j++) ov[j] = f2bf(o[j]);
    *(u16x4*)(att + (size_t)m * D_ + col) = ov;
}

// ---------------- LayerNorm over rows of 768 (bf16 in, f32 out) ----------------
__global__ __launch_bounds__(256) void ln_kernel(const u16* __restrict__ Yb,
                                                 const float* __restrict__ gamma,
                                                 const float* __restrict__ beta,
                                                 float* __restrict__ out) {
    const int row = blockIdx.x;
    const u16* r = Yb + (size_t)row * D_;
    const int t = threadIdx.x;
    const float v0 = bf2f(r[t]), v1 = bf2f(r[t + 256]), v2 = bf2f(r[t + 512]);
    float s  = v0 + v1 + v2;
    float s2 = v0 * v0 + v1 * v1 + v2 * v2;
#pragma unroll
    for (int off = 32; off > 0; off >>= 1) {
        s  += __shfl_xor(s,  off, 64);
        s2 += __shfl_xor(s2, off, 64);
    }
    __shared__ float red[8];
    const int w = t >> 6, l = t & 63;
    if (l == 0) { red[w] = s; red[4 + w] = s2; }
    __syncthreads();
    s  = red[0] + red[1] + red[2] + red[3];
    s2 = red[4] + red[5] + red[6] + red[7];
    const float mu  = s * (1.f / 768.f);
    const float var = s2 * (1.f / 768.f) - mu * mu;
    const float inv = rsqrtf(var + 1e-5f);
    float* o = out + (size_t)row * D_;
    o[t]       = (v0 - mu) * inv * gamma[t]       + beta[t];
    o[t + 256] = (v1 - mu) * inv * gamma[t + 256] + beta[t + 256];
    o[t + 512] = (v2 - mu) * inv * gamma[t + 512] + beta[t + 512];
}

extern "C" void kernel_launch(void* const* d_in, const int* in_sizes, int n_in,
                              void* d_out, int out_size, void* d_ws, size_t ws_size,
                              hipStream_t stream) {
    const float* x     = (const float*)d_in[0];
    const float* Wq    = (const float*)d_in[1];
    const float* bq    = (const float*)d_in[2];
    const float* Wk    = (const float*)d_in[3];
    const float* bk    = (const float*)d_in[4];
    const float* Wv    = (const float*)d_in[5];
    const float* bv    = (const float*)d_in[6];
    const float* Wo    = (const float*)d_in[7];
    const float* bo    = (const float*)d_in[8];
    const float* gamma = (const float*)d_in[9];
    const float* beta  = (const float*)d_in[10];

    char* ws = (char*)d_ws;
    u16*   Wb  = (u16*)ws;                                  //  4,718,592 B
    u16*   xb  = (u16*)(ws + 4718592);                      // 50,331,648 B (stays live)
    u16*   QKV = (u16*)(ws + 4718592 + 50331648);           // 150,994,944 B
    u16*   yb  = QKV;                                       // reuse after attn
    u16*   att = (u16*)d_out;                               // scratch in d_out

    (void)hipFuncSetAttribute(reinterpret_cast<const void*>(&gemmp_kernel<0>),
                              hipFuncAttributeMaxDynamicSharedMemorySize, 65536);
    (void)hipFuncSetAttribute(reinterpret_cast<const void*>(&gemmp_kernel<1>),
                              hipFuncAttributeMaxDynamicSharedMemorySize, 65536);

    castx_kernel<<<(M_ * D_) / (256 * 4), 256, 0, stream>>>(x, xb);
    wtrans_kernel<<<dim3(24, 24, 4), 256, 0, stream>>>(Wq, Wk, Wv, Wo, Wb);
    gemmp_kernel<0><<<512, 512, 65536, stream>>>(xb, Wb, bq, bk, bv, QKV, nullptr);
    attn_kernel<<<(M_ * 3) / 4, 256, 0, stream>>>(QKV, bk, bv, att);
    gemmp_kernel<1><<<512, 512, 65536, stream>>>(att, Wb, bo, nullptr, nullptr,
                                                 yb, xb);
    ln_kernel<<<M_, 256, 0, stream>>>(yb, gamma, beta, (float*)d_out);
}